// Round 1
// baseline (2336.529 us; speedup 1.0000x reference)
//
#include <hip/hip_runtime.h>
#include <math.h>

// Contextual loss, N=1, C=256, H=W=96 → S=9216.
// loss = log(S) - log( sum_j exp( -min_i [ a_i*(d_ij - m_i) + log W_i ] ) )
//   d_ij = clip((1 - cos_ij)/2, 0),  m_i = min_j d_ij,  a_i = 2/(m_i+1e-5),
//   W_i  = sum_j exp(-a_i*(d_ij - m_i))
// cos = Iv^T Tv with Iv,Tv = per-channel-mean-centered, C-normalized features.

static constexpr int Sn = 9216;
static constexpr int Cn = 256;

// ws layout (float offsets)
static constexpr size_t OFF_MEAN = 0;                  // Cn floats
static constexpr size_t OFF_MROW = 256;                // Sn (uint bits, row min of d)
static constexpr size_t OFF_WROW = 256 + 9216;         // Sn floats (row sum exp)
static constexpr size_t OFF_VCOL = 256 + 2 * 9216;     // Sn (uint bits, col min of v)
static constexpr size_t OFF_IV   = 32768;              // Cn*Sn floats
static constexpr size_t OFF_TV   = 32768 + (size_t)Cn * Sn;
// total: 32768 + 2*2359296 floats = 19,005,440 bytes (~18.2 MB) of ws

#define LDA 68   // 64 + 4 pad, keeps 16B alignment of rows (68*4 = 272 = 17*16)

// ---------------- init ----------------
__global__ void k_init(float* ws) {
    int t = blockIdx.x * 256 + threadIdx.x;
    if (t < Sn) {
        ((unsigned*)(ws + OFF_MROW))[t] = 0x7F800000u;  // +inf
        ws[OFF_WROW + t] = 0.0f;
        ((unsigned*)(ws + OFF_VCOL))[t] = 0x7F800000u;  // +inf
    }
}

// ---------------- per-channel mean of T ----------------
__global__ void k_mean(const float* __restrict__ T, float* ws) {
    __shared__ float red[256];
    int c = blockIdx.x;
    float s = 0.f;
    for (int i = threadIdx.x; i < Sn; i += 256) s += T[(size_t)c * Sn + i];
    red[threadIdx.x] = s;
    __syncthreads();
    for (int off = 128; off > 0; off >>= 1) {
        if (threadIdx.x < off) red[threadIdx.x] += red[threadIdx.x + off];
        __syncthreads();
    }
    if (threadIdx.x == 0) ws[OFF_MEAN + c] = red[0] * (1.0f / Sn);
}

// ---------------- center + L2 normalize along C ----------------
__global__ void k_norm(const float* __restrict__ I, const float* __restrict__ T,
                       float* ws) {
    __shared__ float mc[256];
    int s = blockIdx.x * 256 + threadIdx.x;
    mc[threadIdx.x] = ws[OFF_MEAN + threadIdx.x];
    __syncthreads();
    float si = 0.f, st = 0.f;
    for (int c = 0; c < Cn; ++c) {
        float xi = I[(size_t)c * Sn + s] - mc[c];
        float xt = T[(size_t)c * Sn + s] - mc[c];
        si += xi * xi;
        st += xt * xt;
    }
    float ri = 1.0f / fmaxf(sqrtf(si), 1e-12f);
    float rt = 1.0f / fmaxf(sqrtf(st), 1e-12f);
    float* Iv = ws + OFF_IV;
    float* Tv = ws + OFF_TV;
    for (int c = 0; c < Cn; ++c) {
        Iv[(size_t)c * Sn + s] = (I[(size_t)c * Sn + s] - mc[c]) * ri;
        Tv[(size_t)c * Sn + s] = (T[(size_t)c * Sn + s] - mc[c]) * rt;
    }
}

// Shared tile-GEMM body: computes acc[ri][rj] = cos for a 64x64 tile at (i0,j0).
// 256 threads = 16x16, each 4x4 outputs. A from Iv (rows i), B from Tv (cols j).
__device__ __forceinline__ void tile_cos(const float* __restrict__ Iv,
                                         const float* __restrict__ Tv,
                                         float* As, float* Bs,
                                         int i0, int j0, int tid,
                                         float acc[4][4]) {
    const int txi = tid & 15, txj = tid >> 4;
#pragma unroll
    for (int ri = 0; ri < 4; ++ri)
#pragma unroll
        for (int rj = 0; rj < 4; ++rj) acc[ri][rj] = 0.f;

    for (int kc = 0; kc < 4; ++kc) {
        int k0 = kc * 64;
        __syncthreads();  // protect LDS from previous iteration's readers
#pragma unroll
        for (int r = 0; r < 4; ++r) {
            int kk = (tid >> 4) + r * 16;
            int ii = (tid & 15) * 4;
            float4 av = *(const float4*)&Iv[(size_t)(k0 + kk) * Sn + i0 + ii];
            *(float4*)&As[kk * LDA + ii] = av;
            float4 bv = *(const float4*)&Tv[(size_t)(k0 + kk) * Sn + j0 + ii];
            *(float4*)&Bs[kk * LDA + ii] = bv;
        }
        __syncthreads();
#pragma unroll 8
        for (int kk = 0; kk < 64; ++kk) {
            float4 a = *(const float4*)&As[kk * LDA + 4 * txi];
            float4 b = *(const float4*)&Bs[kk * LDA + 4 * txj];
            float ar[4] = {a.x, a.y, a.z, a.w};
            float br[4] = {b.x, b.y, b.z, b.w};
#pragma unroll
            for (int ri = 0; ri < 4; ++ri)
#pragma unroll
                for (int rj = 0; rj < 4; ++rj) acc[ri][rj] += ar[ri] * br[rj];
        }
    }
}

// ---------------- pass 1: m_i = min_j d_ij ----------------
__global__ __launch_bounds__(256) void k_rowmin(float* ws) {
    __shared__ float As[64 * LDA];
    __shared__ float Bs[64 * LDA];
    __shared__ float red[64 * 17];
    const float* Iv = ws + OFF_IV;
    const float* Tv = ws + OFF_TV;
    const int tid = threadIdx.x, txi = tid & 15, txj = tid >> 4;
    const int i0 = blockIdx.x * 64;
    float mv[4] = {INFINITY, INFINITY, INFINITY, INFINITY};
    float acc[4][4];
    for (int jt = 0; jt < 36; ++jt) {
        int j0 = blockIdx.y * 2304 + jt * 64;
        tile_cos(Iv, Tv, As, Bs, i0, j0, tid, acc);
#pragma unroll
        for (int ri = 0; ri < 4; ++ri)
#pragma unroll
            for (int rj = 0; rj < 4; ++rj) {
                float d = fmaxf((1.0f - acc[ri][rj]) * 0.5f, 0.0f);
                mv[ri] = fminf(mv[ri], d);
            }
    }
    __syncthreads();
#pragma unroll
    for (int ri = 0; ri < 4; ++ri) red[(4 * txi + ri) * 17 + txj] = mv[ri];
    __syncthreads();
    if (tid < 64) {
        float m = red[tid * 17];
        for (int t = 1; t < 16; ++t) m = fminf(m, red[tid * 17 + t]);
        atomicMin((unsigned*)(ws + OFF_MROW) + i0 + tid, __float_as_uint(m));
    }
}

// ---------------- pass 2: W_i = sum_j exp(-a_i (d_ij - m_i)) ----------------
__global__ __launch_bounds__(256) void k_rowsum(float* ws) {
    __shared__ float As[64 * LDA];
    __shared__ float Bs[64 * LDA];
    __shared__ float red[64 * 17];
    const float* Iv = ws + OFF_IV;
    const float* Tv = ws + OFF_TV;
    const int tid = threadIdx.x, txi = tid & 15, txj = tid >> 4;
    const int i0 = blockIdx.x * 64;
    float m[4], a[4], sum[4] = {0.f, 0.f, 0.f, 0.f};
#pragma unroll
    for (int r = 0; r < 4; ++r) {
        float mm = __uint_as_float(((unsigned*)(ws + OFF_MROW))[i0 + 4 * txi + r]);
        m[r] = mm;
        a[r] = 2.0f / (mm + 1e-5f);
    }
    float acc[4][4];
    for (int jt = 0; jt < 36; ++jt) {
        int j0 = blockIdx.y * 2304 + jt * 64;
        tile_cos(Iv, Tv, As, Bs, i0, j0, tid, acc);
#pragma unroll
        for (int ri = 0; ri < 4; ++ri)
#pragma unroll
            for (int rj = 0; rj < 4; ++rj) {
                float d = fmaxf((1.0f - acc[ri][rj]) * 0.5f, 0.0f);
                sum[ri] += __expf(-a[ri] * (d - m[ri]));
            }
    }
    __syncthreads();
#pragma unroll
    for (int ri = 0; ri < 4; ++ri) red[(4 * txi + ri) * 17 + txj] = sum[ri];
    __syncthreads();
    if (tid < 64) {
        float s = 0.f;
        for (int t = 0; t < 16; ++t) s += red[tid * 17 + t];
        atomicAdd(&ws[OFF_WROW + i0 + tid], s);
    }
}

// ---------------- pass 3: vcol_j = min_i [ a_i (d_ij - m_i) + log W_i ] ----
__global__ __launch_bounds__(256) void k_colmin(float* ws) {
    __shared__ float As[64 * LDA];
    __shared__ float Bs[64 * LDA];
    __shared__ float red[64 * 17];
    const float* Iv = ws + OFF_IV;
    const float* Tv = ws + OFF_TV;
    const int tid = threadIdx.x, txi = tid & 15, txj = tid >> 4;
    const int j0 = blockIdx.x * 64;
    float cmin[4] = {INFINITY, INFINITY, INFINITY, INFINITY};
    float acc[4][4];
    for (int it = 0; it < 36; ++it) {
        int i0 = blockIdx.y * 2304 + it * 64;
        tile_cos(Iv, Tv, As, Bs, i0, j0, tid, acc);
        float m[4], a[4], lw[4];
#pragma unroll
        for (int r = 0; r < 4; ++r) {
            int i = i0 + 4 * txi + r;
            float mm = __uint_as_float(((unsigned*)(ws + OFF_MROW))[i]);
            m[r] = mm;
            a[r] = 2.0f / (mm + 1e-5f);
            lw[r] = logf(ws[OFF_WROW + i]);
        }
#pragma unroll
        for (int ri = 0; ri < 4; ++ri)
#pragma unroll
            for (int rj = 0; rj < 4; ++rj) {
                float d = fmaxf((1.0f - acc[ri][rj]) * 0.5f, 0.0f);
                float v = a[ri] * (d - m[ri]) + lw[ri];
                cmin[rj] = fminf(cmin[rj], v);
            }
    }
    __syncthreads();
#pragma unroll
    for (int rj = 0; rj < 4; ++rj) red[(4 * txj + rj) * 17 + txi] = cmin[rj];
    __syncthreads();
    if (tid < 64) {
        float v = red[tid * 17];
        for (int t = 1; t < 16; ++t) v = fminf(v, red[tid * 17 + t]);
        atomicMin((unsigned*)(ws + OFF_VCOL) + j0 + tid, __float_as_uint(v));
    }
}

// ---------------- final: loss = log(S) - log(sum_j exp(-vcol_j)) ----------
__global__ void k_final(const float* __restrict__ ws, float* __restrict__ out) {
    __shared__ float red[256];
    float s = 0.f;
    for (int j = threadIdx.x; j < Sn; j += 256)
        s += expf(-__uint_as_float(((const unsigned*)(ws + OFF_VCOL))[j]));
    red[threadIdx.x] = s;
    __syncthreads();
    for (int off = 128; off > 0; off >>= 1) {
        if (threadIdx.x < off) red[threadIdx.x] += red[threadIdx.x + off];
        __syncthreads();
    }
    if (threadIdx.x == 0) out[0] = logf((float)Sn) - logf(red[0]);
}

extern "C" void kernel_launch(void* const* d_in, const int* in_sizes, int n_in,
                              void* d_out, int out_size, void* d_ws, size_t ws_size,
                              hipStream_t stream) {
    const float* I = (const float*)d_in[0];
    const float* T = (const float*)d_in[1];
    float* ws = (float*)d_ws;
    float* out = (float*)d_out;

    k_init<<<36, 256, 0, stream>>>(ws);
    k_mean<<<Cn, 256, 0, stream>>>(T, ws);
    k_norm<<<Sn / 256, 256, 0, stream>>>(I, T, ws);
    k_rowmin<<<dim3(144, 4), 256, 0, stream>>>(ws);
    k_rowsum<<<dim3(144, 4), 256, 0, stream>>>(ws);
    k_colmin<<<dim3(144, 4), 256, 0, stream>>>(ws);
    k_final<<<1, 256, 0, stream>>>(ws, out);
}

// Round 2
// 363.218 us; speedup vs baseline: 6.4329x; 6.4329x over previous
//
#include <hip/hip_runtime.h>
#include <math.h>

// Contextual loss, N=1, C=256, H=W=96 -> S=9216.
// loss = log(S) - log( sum_j exp( -min_i [ a_i*(d_ij - m_i) + log W_i ] ) )
//   d_ij = clip((1 - cos_ij)/2, 0),  m_i = min_j d_ij,  a_i = 2/(m_i+1e-5),
//   W_i  = sum_j exp(-a_i*(d_ij - m_i))
// cos = Iv^T Tv; Iv,Tv = mean_T-centered, C-normalized features, stored
// TRANSPOSED [S][C] in bf16 so both MFMA operands are K-contiguous (NT GEMM).

typedef short v8s __attribute__((ext_vector_type(8)));
typedef float v4f __attribute__((ext_vector_type(4)));

static constexpr int Sn = 9216;
static constexpr int Cn = 256;

// ws float offsets
static constexpr size_t OFF_MEAN = 0;                      // 256 floats
static constexpr size_t OFF_MROW = 256;                    // Sn uint bits (row min d)
static constexpr size_t OFF_WROW = 256 + 9216;             // Sn floats (row sumexp)
static constexpr size_t OFF_VCOL = 256 + 2 * 9216;         // Sn uint bits (col min v)
static constexpr size_t OFF_IV   = 32768;                  // Sn*Cn bf16 (ushort)
static constexpr size_t OFF_TV   = 32768 + (size_t)Sn * Cn / 2;  // float offset
// total ~9.6 MB of ws

__device__ __forceinline__ unsigned bf16rne(float x) {
    unsigned u = __float_as_uint(x);
    return (u + 0x7FFFu + ((u >> 16) & 1u)) >> 16;
}

// ---------------- init ----------------
__global__ void k_init(float* ws) {
    int t = blockIdx.x * 256 + threadIdx.x;
    if (t < Sn) {
        ((unsigned*)(ws + OFF_MROW))[t] = 0x7F800000u;  // +inf
        ws[OFF_WROW + t] = 0.0f;
        ((unsigned*)(ws + OFF_VCOL))[t] = 0x7F800000u;  // +inf
    }
}

// ---------------- per-channel mean of T ----------------
__global__ void k_mean(const float* __restrict__ T, float* ws) {
    __shared__ float red[256];
    int c = blockIdx.x;
    float s = 0.f;
    for (int i = threadIdx.x; i < Sn; i += 256) s += T[(size_t)c * Sn + i];
    red[threadIdx.x] = s;
    __syncthreads();
    for (int off = 128; off > 0; off >>= 1) {
        if (threadIdx.x < off) red[threadIdx.x] += red[threadIdx.x + off];
        __syncthreads();
    }
    if (threadIdx.x == 0) ws[OFF_MEAN + c] = red[0] * (1.0f / Sn);
}

// ------- center + L2 normalize along C, emit bf16 transposed [S][C] -------
__global__ void k_norm(const float* __restrict__ I, const float* __restrict__ T,
                       float* ws) {
    __shared__ float mc[256];
    int s = blockIdx.x * 256 + threadIdx.x;
    mc[threadIdx.x] = ws[OFF_MEAN + threadIdx.x];
    __syncthreads();
    float si = 0.f, st = 0.f;
    for (int c = 0; c < Cn; ++c) {
        float xi = I[(size_t)c * Sn + s] - mc[c];
        float xt = T[(size_t)c * Sn + s] - mc[c];
        si += xi * xi;
        st += xt * xt;
    }
    float ri = 1.0f / fmaxf(sqrtf(si), 1e-12f);
    float rt = 1.0f / fmaxf(sqrtf(st), 1e-12f);
    unsigned short* Iv = (unsigned short*)(ws + OFF_IV);
    unsigned short* Tv = (unsigned short*)(ws + OFF_TV);
    uint4* Ivq = (uint4*)(Iv + (size_t)s * Cn);
    uint4* Tvq = (uint4*)(Tv + (size_t)s * Cn);
    for (int c8 = 0; c8 < Cn / 8; ++c8) {
        unsigned iw[4], tw[4];
#pragma unroll
        for (int h = 0; h < 4; ++h) {
            int c0 = c8 * 8 + 2 * h, c1 = c0 + 1;
            float i0 = (I[(size_t)c0 * Sn + s] - mc[c0]) * ri;
            float i1 = (I[(size_t)c1 * Sn + s] - mc[c1]) * ri;
            float t0 = (T[(size_t)c0 * Sn + s] - mc[c0]) * rt;
            float t1 = (T[(size_t)c1 * Sn + s] - mc[c1]) * rt;
            iw[h] = bf16rne(i0) | (bf16rne(i1) << 16);
            tw[h] = bf16rne(t0) | (bf16rne(t1) << 16);
        }
        Ivq[c8] = make_uint4(iw[0], iw[1], iw[2], iw[3]);
        Tvq[c8] = make_uint4(tw[0], tw[1], tw[2], tw[3]);
    }
}

// ---- 128x128 bf16 MFMA tile, full K=256: acc[mt][nt] C-frag for this wave ----
// A rows row0..row0+127 of Abuf [S][C]; B rows col0..col0+127 of Bbuf [S][C].
// Output D[row][col]: row = wm*64+mt*16+quad*4+reg, col = wn*64+nt*16+l15.
__device__ __forceinline__ void mma_tile(const unsigned short* __restrict__ A,
                                         const unsigned short* __restrict__ B,
                                         char* Asb, char* Bsb,
                                         int row0, int col0, int tid,
                                         v4f acc[4][4]) {
    const int lane = tid & 63, wave = tid >> 6;
    const int wm = wave >> 1, wn = wave & 1;
    const int quad = lane >> 4, l15 = lane & 15;
#pragma unroll
    for (int a = 0; a < 4; ++a)
#pragma unroll
        for (int b = 0; b < 4; ++b)
#pragma unroll
            for (int r = 0; r < 4; ++r) acc[a][b][r] = 0.f;

    const uint4* Aq = (const uint4*)A;
    const uint4* Bq = (const uint4*)B;
    for (int kc = 0; kc < 4; ++kc) {
        __syncthreads();
        uint4 av[4], bv[4];
#pragma unroll
        for (int p = 0; p < 4; ++p) {
            int idx = p * 256 + tid;
            int r = idx >> 3, c16 = idx & 7;
            av[p] = Aq[(size_t)(row0 + r) * 32 + kc * 8 + c16];
            bv[p] = Bq[(size_t)(col0 + r) * 32 + kc * 8 + c16];
        }
#pragma unroll
        for (int p = 0; p < 4; ++p) {
            int idx = p * 256 + tid;
            int r = idx >> 3, c16 = idx & 7;
            ((uint4*)Asb)[r * 8 + (c16 ^ (r & 7))] = av[p];
            ((uint4*)Bsb)[r * 8 + (c16 ^ (r & 7))] = bv[p];
        }
        __syncthreads();
#pragma unroll
        for (int ks = 0; ks < 2; ++ks) {
            v8s fa[4], fb[4];
#pragma unroll
            for (int mt = 0; mt < 4; ++mt) {
                int row = wm * 64 + mt * 16 + l15;
                int chunk = (ks * 4 + quad) ^ (row & 7);
                fa[mt] = *(const v8s*)(Asb + row * 128 + chunk * 16);
            }
#pragma unroll
            for (int nt = 0; nt < 4; ++nt) {
                int row = wn * 64 + nt * 16 + l15;
                int chunk = (ks * 4 + quad) ^ (row & 7);
                fb[nt] = *(const v8s*)(Bsb + row * 128 + chunk * 16);
            }
#pragma unroll
            for (int mt = 0; mt < 4; ++mt)
#pragma unroll
                for (int nt = 0; nt < 4; ++nt)
                    acc[mt][nt] = __builtin_amdgcn_mfma_f32_16x16x32_bf16(
                        fa[mt], fb[nt], acc[mt][nt], 0, 0, 0);
        }
    }
}

// ---------------- pass 1: m_i = min_j d_ij ----------------
__global__ __launch_bounds__(256) void k_rowmin(float* ws) {
    __shared__ __align__(16) char Asb[16384];
    __shared__ __align__(16) char Bsb[16384];
    const unsigned short* Iv = (const unsigned short*)(ws + OFF_IV);
    const unsigned short* Tv = (const unsigned short*)(ws + OFF_TV);
    const int tid = threadIdx.x, lane = tid & 63, wave = tid >> 6;
    const int wm = wave >> 1, quad = lane >> 4, l15 = lane & 15;
    const int i0 = blockIdx.x * 128;
    float mv[4][4];
#pragma unroll
    for (int mt = 0; mt < 4; ++mt)
#pragma unroll
        for (int r = 0; r < 4; ++r) mv[mt][r] = INFINITY;
    v4f acc[4][4];
    for (int jt = 0; jt < 4; ++jt) {
        int j0 = (blockIdx.y * 4 + jt) * 128;
        mma_tile(Iv, Tv, Asb, Bsb, i0, j0, tid, acc);
#pragma unroll
        for (int mt = 0; mt < 4; ++mt)
#pragma unroll
            for (int nt = 0; nt < 4; ++nt)
#pragma unroll
                for (int r = 0; r < 4; ++r) {
                    float d = fmaxf((1.0f - acc[mt][nt][r]) * 0.5f, 0.0f);
                    mv[mt][r] = fminf(mv[mt][r], d);
                }
    }
#pragma unroll
    for (int mt = 0; mt < 4; ++mt)
#pragma unroll
        for (int r = 0; r < 4; ++r) {
            float m = mv[mt][r];
            for (int off = 1; off < 16; off <<= 1)
                m = fminf(m, __shfl_xor(m, off, 64));
            if (l15 == 0)
                atomicMin((unsigned*)(ws + OFF_MROW) + i0 + wm * 64 + mt * 16 + quad * 4 + r,
                          __float_as_uint(m));
        }
}

// ---------------- pass 2: W_i = sum_j exp(-a_i (d_ij - m_i)) ----------------
__global__ __launch_bounds__(256) void k_rowsum(float* ws) {
    __shared__ __align__(16) char Asb[16384];
    __shared__ __align__(16) char Bsb[16384];
    const unsigned short* Iv = (const unsigned short*)(ws + OFF_IV);
    const unsigned short* Tv = (const unsigned short*)(ws + OFF_TV);
    const int tid = threadIdx.x, lane = tid & 63, wave = tid >> 6;
    const int wm = wave >> 1, quad = lane >> 4, l15 = lane & 15;
    const int i0 = blockIdx.x * 128;
    float m[4][4], ai[4][4], run[4][4];
#pragma unroll
    for (int mt = 0; mt < 4; ++mt)
#pragma unroll
        for (int r = 0; r < 4; ++r) {
            int i = i0 + wm * 64 + mt * 16 + quad * 4 + r;
            float mm = __uint_as_float(((unsigned*)(ws + OFF_MROW))[i]);
            m[mt][r] = mm;
            ai[mt][r] = 2.0f / (mm + 1e-5f);
            run[mt][r] = 0.f;
        }
    v4f acc[4][4];
    for (int jt = 0; jt < 4; ++jt) {
        int j0 = (blockIdx.y * 4 + jt) * 128;
        mma_tile(Iv, Tv, Asb, Bsb, i0, j0, tid, acc);
#pragma unroll
        for (int mt = 0; mt < 4; ++mt)
#pragma unroll
            for (int nt = 0; nt < 4; ++nt)
#pragma unroll
                for (int r = 0; r < 4; ++r) {
                    float d = fmaxf((1.0f - acc[mt][nt][r]) * 0.5f, 0.0f);
                    run[mt][r] += __expf(-ai[mt][r] * (d - m[mt][r]));
                }
    }
#pragma unroll
    for (int mt = 0; mt < 4; ++mt)
#pragma unroll
        for (int r = 0; r < 4; ++r) {
            float s = run[mt][r];
            for (int off = 1; off < 16; off <<= 1)
                s += __shfl_xor(s, off, 64);
            if (l15 == 0)
                atomicAdd(ws + OFF_WROW + i0 + wm * 64 + mt * 16 + quad * 4 + r, s);
        }
}

// ------- pass 3: vcol_j = min_i [ a_i (d_ij - m_i) + log W_i ] -------------
// Transposed orientation: block rows = j (from Tv), cols = i (from Iv).
__global__ __launch_bounds__(256) void k_colmin(float* ws) {
    __shared__ __align__(16) char Asb[16384];
    __shared__ __align__(16) char Bsb[16384];
    const unsigned short* Iv = (const unsigned short*)(ws + OFF_IV);
    const unsigned short* Tv = (const unsigned short*)(ws + OFF_TV);
    const int tid = threadIdx.x, lane = tid & 63, wave = tid >> 6;
    const int wm = wave >> 1, wn = wave & 1, quad = lane >> 4, l15 = lane & 15;
    const int j0 = blockIdx.x * 128;
    float vmin[4][4];
#pragma unroll
    for (int mt = 0; mt < 4; ++mt)
#pragma unroll
        for (int r = 0; r < 4; ++r) vmin[mt][r] = INFINITY;
    v4f acc[4][4];
    for (int it = 0; it < 4; ++it) {
        int i0 = (blockIdx.y * 4 + it) * 128;
        mma_tile(Tv, Iv, Asb, Bsb, j0, i0, tid, acc);  // acc = cos[j][i]
#pragma unroll
        for (int nt = 0; nt < 4; ++nt) {
            int i = i0 + wn * 64 + nt * 16 + l15;
            float mm = __uint_as_float(((unsigned*)(ws + OFF_MROW))[i]);
            float a = 2.0f / (mm + 1e-5f);
            float lw = logf(ws[OFF_WROW + i]);
#pragma unroll
            for (int mt = 0; mt < 4; ++mt)
#pragma unroll
                for (int r = 0; r < 4; ++r) {
                    float d = fmaxf((1.0f - acc[mt][nt][r]) * 0.5f, 0.0f);
                    float v = a * (d - mm) + lw;
                    vmin[mt][r] = fminf(vmin[mt][r], v);
                }
        }
    }
#pragma unroll
    for (int mt = 0; mt < 4; ++mt)
#pragma unroll
        for (int r = 0; r < 4; ++r) {
            float v = vmin[mt][r];
            for (int off = 1; off < 16; off <<= 1)
                v = fminf(v, __shfl_xor(v, off, 64));
            if (l15 == 0)
                atomicMin((unsigned*)(ws + OFF_VCOL) + j0 + wm * 64 + mt * 16 + quad * 4 + r,
                          __float_as_uint(v));
        }
}

// ---------------- final: loss = log(S) - log(sum_j exp(-vcol_j)) ----------
__global__ void k_final(const float* __restrict__ ws, float* __restrict__ out) {
    __shared__ float red[256];
    float s = 0.f;
    for (int j = threadIdx.x; j < Sn; j += 256)
        s += expf(-__uint_as_float(((const unsigned*)(ws + OFF_VCOL))[j]));
    red[threadIdx.x] = s;
    __syncthreads();
    for (int off = 128; off > 0; off >>= 1) {
        if (threadIdx.x < off) red[threadIdx.x] += red[threadIdx.x + off];
        __syncthreads();
    }
    if (threadIdx.x == 0) out[0] = logf((float)Sn) - logf(red[0]);
}

extern "C" void kernel_launch(void* const* d_in, const int* in_sizes, int n_in,
                              void* d_out, int out_size, void* d_ws, size_t ws_size,
                              hipStream_t stream) {
    const float* I = (const float*)d_in[0];
    const float* T = (const float*)d_in[1];
    float* ws = (float*)d_ws;
    float* out = (float*)d_out;

    k_init<<<36, 256, 0, stream>>>(ws);
    k_mean<<<Cn, 256, 0, stream>>>(T, ws);
    k_norm<<<Sn / 256, 256, 0, stream>>>(I, T, ws);
    k_rowmin<<<dim3(72, 18), 256, 0, stream>>>(ws);
    k_rowsum<<<dim3(72, 18), 256, 0, stream>>>(ws);
    k_colmin<<<dim3(72, 18), 256, 0, stream>>>(ws);
    k_final<<<1, 256, 0, stream>>>(ws, out);
}

// Round 3
// 325.479 us; speedup vs baseline: 7.1787x; 1.1159x over previous
//
#include <hip/hip_runtime.h>
#include <math.h>

// Contextual loss, N=1, C=256, H=W=96 -> S=9216.
// loss = log(S) - log( sum_j exp( -vcol_j ) )
//   vcol_j = min_i [ a_i * d_ij + ln S'_i ]
//   S'_i   = sum_j exp( -a_i * d_ij )
//   a_i    = 2 / (m_i + 1e-5),  m_i = min_j d_ij,  d = clip((1-cos)/2, 0)
// (m_i cancels out of v: a(d-m)+log W = a*d + ln S' with W = e^{a m} S'.)
// cos = Iv^T Tv; Iv,Tv bf16, stored transposed [S][C] (K-contiguous, NT GEMM).

typedef short v8s __attribute__((ext_vector_type(8)));
typedef float v4f __attribute__((ext_vector_type(4)));

static constexpr int Sn = 9216;
static constexpr int Cn = 256;

// ws float offsets
static constexpr size_t OFF_MEAN = 0;                      // 256 floats
static constexpr size_t OFF_MROW = 256;                    // Sn uint bits (row min d)
static constexpr size_t OFF_WROW = 256 + 9216;             // Sn floats (S'_i)
static constexpr size_t OFF_VCOL = 256 + 2 * 9216;         // Sn uint bits (col min v)
static constexpr size_t OFF_IV   = 32768;                  // Sn*Cn bf16
static constexpr size_t OFF_TV   = 32768 + (size_t)Sn * Cn / 2;

__device__ __forceinline__ unsigned bf16rne(float x) {
    unsigned u = __float_as_uint(x);
    return (u + 0x7FFFu + ((u >> 16) & 1u)) >> 16;
}

__device__ __forceinline__ void gload_lds16(const void* g, void* l) {
    __builtin_amdgcn_global_load_lds(
        (const __attribute__((address_space(1))) unsigned*)g,
        (__attribute__((address_space(3))) unsigned*)l, 16, 0, 0);
}

// ---------------- init ----------------
__global__ void k_init(float* ws) {
    int t = blockIdx.x * 256 + threadIdx.x;
    if (t < Sn) {
        ((unsigned*)(ws + OFF_MROW))[t] = 0x7F800000u;  // +inf
        ws[OFF_WROW + t] = 0.0f;
        ((unsigned*)(ws + OFF_VCOL))[t] = 0x7F800000u;  // +inf
    }
}

// ---------------- per-channel mean of T ----------------
__global__ void k_mean(const float* __restrict__ T, float* ws) {
    __shared__ float red[256];
    int c = blockIdx.x;
    float s = 0.f;
    for (int i = threadIdx.x; i < Sn; i += 256) s += T[(size_t)c * Sn + i];
    red[threadIdx.x] = s;
    __syncthreads();
    for (int off = 128; off > 0; off >>= 1) {
        if (threadIdx.x < off) red[threadIdx.x] += red[threadIdx.x + off];
        __syncthreads();
    }
    if (threadIdx.x == 0) ws[OFF_MEAN + c] = red[0] * (1.0f / Sn);
}

// ------- center + L2 normalize along C, emit bf16 transposed [S][C] -------
__global__ void k_norm(const float* __restrict__ I, const float* __restrict__ T,
                       float* ws) {
    __shared__ float mc[256];
    int s = blockIdx.x * 256 + threadIdx.x;
    mc[threadIdx.x] = ws[OFF_MEAN + threadIdx.x];
    __syncthreads();
    float si = 0.f, st = 0.f;
    for (int c = 0; c < Cn; ++c) {
        float xi = I[(size_t)c * Sn + s] - mc[c];
        float xt = T[(size_t)c * Sn + s] - mc[c];
        si += xi * xi;
        st += xt * xt;
    }
    float ri = 1.0f / fmaxf(sqrtf(si), 1e-12f);
    float rt = 1.0f / fmaxf(sqrtf(st), 1e-12f);
    unsigned short* Iv = (unsigned short*)(ws + OFF_IV);
    unsigned short* Tv = (unsigned short*)(ws + OFF_TV);
    uint4* Ivq = (uint4*)(Iv + (size_t)s * Cn);
    uint4* Tvq = (uint4*)(Tv + (size_t)s * Cn);
    for (int c8 = 0; c8 < Cn / 8; ++c8) {
        unsigned iw[4], tw[4];
#pragma unroll
        for (int h = 0; h < 4; ++h) {
            int c0 = c8 * 8 + 2 * h, c1 = c0 + 1;
            float i0 = (I[(size_t)c0 * Sn + s] - mc[c0]) * ri;
            float i1 = (I[(size_t)c1 * Sn + s] - mc[c1]) * ri;
            float t0 = (T[(size_t)c0 * Sn + s] - mc[c0]) * rt;
            float t1 = (T[(size_t)c1 * Sn + s] - mc[c1]) * rt;
            iw[h] = bf16rne(i0) | (bf16rne(i1) << 16);
            tw[h] = bf16rne(t0) | (bf16rne(t1) << 16);
        }
        Ivq[c8] = make_uint4(iw[0], iw[1], iw[2], iw[3]);
        Tvq[c8] = make_uint4(tw[0], tw[1], tw[2], tw[3]);
    }
}

// Stage one K-slice (64 ch = 128 B) of 128 rows into 16 KB LDS via
// global_load_lds, with chunk swizzle p = c ^ (row&7) applied on the
// global gather side (LDS dest is wave-uniform base + lane*16).
// Gb = global byte ptr to row0's K=0. LDS layout: [row][8 phys chunks of 16B].
__device__ __forceinline__ void stage_slice(const char* Gb, char* lds,
                                            int kcs, int tid) {
    const int lane = tid & 63, wave = tid >> 6;
#pragma unroll
    for (int w = 0; w < 4; ++w) {
        int gi = wave * 4 + w;
        int row = gi * 8 + (lane >> 3);
        int p = lane & 7;
        int c = p ^ (row & 7);
        const char* g = Gb + (size_t)row * 512 + kcs * 128 + c * 16;
        gload_lds16(g, lds + gi * 1024);
    }
}

// Load this wave's A fragments for the full K=256 into registers,
// using the (shared) LDS buffer as a transit.  fa[mt][kk], kk = kcs*2+ks.
__device__ __forceinline__ void load_A_frags(const char* Ab, char* lds,
                                             int tid, v8s fa[4][8]) {
    const int lane = tid & 63, wave = tid >> 6;
    const int wm = wave >> 1, quad = (lane >> 4) & 3, l15 = lane & 15;
#pragma unroll
    for (int kcs = 0; kcs < 4; ++kcs) {
        __syncthreads();
        stage_slice(Ab, lds, kcs, tid);
        __syncthreads();
#pragma unroll
        for (int ks = 0; ks < 2; ++ks) {
            int c = ks * 4 + quad;
#pragma unroll
            for (int mt = 0; mt < 4; ++mt) {
                int row = wm * 64 + mt * 16 + l15;
                int p = c ^ (row & 7);
                fa[mt][kcs * 2 + ks] = *(const v8s*)(lds + row * 128 + p * 16);
            }
        }
    }
}

// One 128x128 tile: stream B (rows col0..col0+127 of Bb) through LDS,
// MFMA against resident fa.  acc must be pre-zeroed by caller.
__device__ __forceinline__ void tile_mma(const char* Bb, char* lds, int tid,
                                         const v8s fa[4][8], v4f acc[4][4]) {
    const int lane = tid & 63, wave = tid >> 6;
    const int wn = wave & 1, quad = (lane >> 4) & 3, l15 = lane & 15;
#pragma unroll
    for (int kc = 0; kc < 4; ++kc) {
        __syncthreads();
        stage_slice(Bb, lds, kc, tid);
        __syncthreads();
#pragma unroll
        for (int ks = 0; ks < 2; ++ks) {
            int c = ks * 4 + quad;
#pragma unroll
            for (int nt = 0; nt < 4; ++nt) {
                int row = wn * 64 + nt * 16 + l15;
                int p = c ^ (row & 7);
                v8s fb = *(const v8s*)(lds + row * 128 + p * 16);
#pragma unroll
                for (int mt = 0; mt < 4; ++mt)
                    acc[mt][nt] = __builtin_amdgcn_mfma_f32_16x16x32_bf16(
                        fa[mt][kc * 2 + ks], fb, acc[mt][nt], 0, 0, 0);
            }
        }
    }
}

// ---------------- pass 1: m_i = min_j d_ij ----------------
__global__ __launch_bounds__(256, 2) void k_rowmin(float* ws) {
    __shared__ __align__(16) char Bsb[16384];
    const char* Ivb = (const char*)(ws + OFF_IV);
    const char* Tvb = (const char*)(ws + OFF_TV);
    const int tid = threadIdx.x, lane = tid & 63, wave = tid >> 6;
    const int wm = wave >> 1, quad = (lane >> 4) & 3, l15 = lane & 15;
    const int i0 = blockIdx.x * 128;
    v8s fa[4][8];
    load_A_frags(Ivb + (size_t)i0 * 512, Bsb, tid, fa);
    float mv[4][4];
#pragma unroll
    for (int mt = 0; mt < 4; ++mt)
#pragma unroll
        for (int r = 0; r < 4; ++r) mv[mt][r] = INFINITY;
    for (int t = 0; t < 9; ++t) {
        int j0 = (blockIdx.y * 9 + t) * 128;
        v4f acc[4][4];
#pragma unroll
        for (int mt = 0; mt < 4; ++mt)
#pragma unroll
            for (int nt = 0; nt < 4; ++nt)
#pragma unroll
                for (int r = 0; r < 4; ++r) acc[mt][nt][r] = 0.f;
        tile_mma(Tvb + (size_t)j0 * 512, Bsb, tid, fa, acc);
#pragma unroll
        for (int mt = 0; mt < 4; ++mt)
#pragma unroll
            for (int nt = 0; nt < 4; ++nt)
#pragma unroll
                for (int r = 0; r < 4; ++r) {
                    float d = fmaxf(0.5f - 0.5f * acc[mt][nt][r], 0.0f);
                    mv[mt][r] = fminf(mv[mt][r], d);
                }
    }
#pragma unroll
    for (int mt = 0; mt < 4; ++mt)
#pragma unroll
        for (int r = 0; r < 4; ++r) {
            float m = mv[mt][r];
            for (int off = 1; off < 16; off <<= 1)
                m = fminf(m, __shfl_xor(m, off, 64));
            if (l15 == 0)
                atomicMin((unsigned*)(ws + OFF_MROW) + i0 + wm * 64 + mt * 16 + quad * 4 + r,
                          __float_as_uint(m));
        }
}

// ---------------- pass 2: S'_i = sum_j exp(-a_i * d_ij) ----------------
__global__ __launch_bounds__(256, 2) void k_rowsum(float* ws) {
    __shared__ __align__(16) char Bsb[16384];
    const char* Ivb = (const char*)(ws + OFF_IV);
    const char* Tvb = (const char*)(ws + OFF_TV);
    const int tid = threadIdx.x, lane = tid & 63, wave = tid >> 6;
    const int wm = wave >> 1, quad = (lane >> 4) & 3, l15 = lane & 15;
    const int i0 = blockIdx.x * 128;
    v8s fa[4][8];
    load_A_frags(Ivb + (size_t)i0 * 512, Bsb, tid, fa);
    float c1[4][4], run[4][4];
#pragma unroll
    for (int mt = 0; mt < 4; ++mt)
#pragma unroll
        for (int r = 0; r < 4; ++r) {
            int i = i0 + wm * 64 + mt * 16 + quad * 4 + r;
            float mm = __uint_as_float(((unsigned*)(ws + OFF_MROW))[i]);
            c1[mt][r] = -1.4426950408889634f * 2.0f / (mm + 1e-5f);  // -a*log2e
            run[mt][r] = 0.f;
        }
    for (int t = 0; t < 9; ++t) {
        int j0 = (blockIdx.y * 9 + t) * 128;
        v4f acc[4][4];
#pragma unroll
        for (int mt = 0; mt < 4; ++mt)
#pragma unroll
            for (int nt = 0; nt < 4; ++nt)
#pragma unroll
                for (int r = 0; r < 4; ++r) acc[mt][nt][r] = 0.f;
        tile_mma(Tvb + (size_t)j0 * 512, Bsb, tid, fa, acc);
#pragma unroll
        for (int mt = 0; mt < 4; ++mt)
#pragma unroll
            for (int nt = 0; nt < 4; ++nt)
#pragma unroll
                for (int r = 0; r < 4; ++r) {
                    float d = fmaxf(0.5f - 0.5f * acc[mt][nt][r], 0.0f);
                    run[mt][r] += __builtin_amdgcn_exp2f(c1[mt][r] * d);
                }
    }
#pragma unroll
    for (int mt = 0; mt < 4; ++mt)
#pragma unroll
        for (int r = 0; r < 4; ++r) {
            float s = run[mt][r];
            for (int off = 1; off < 16; off <<= 1)
                s += __shfl_xor(s, off, 64);
            if (l15 == 0)
                atomicAdd(ws + OFF_WROW + i0 + wm * 64 + mt * 16 + quad * 4 + r, s);
        }
}

// ------- pass 3: vcol_j = min_i [ a_i * d_ij + ln S'_i ] -------------
// Rows of the tile = j (A from Tv), cols = i (B from Iv).
__global__ __launch_bounds__(256, 2) void k_colmin(float* ws) {
    __shared__ __align__(16) char Bsb[16384];
    const char* Ivb = (const char*)(ws + OFF_IV);
    const char* Tvb = (const char*)(ws + OFF_TV);
    const int tid = threadIdx.x, lane = tid & 63, wave = tid >> 6;
    const int wm = wave >> 1, wn = wave & 1, quad = (lane >> 4) & 3, l15 = lane & 15;
    const int j0 = blockIdx.x * 128;
    v8s fa[4][8];
    load_A_frags(Tvb + (size_t)j0 * 512, Bsb, tid, fa);
    float vmin[4][4];
#pragma unroll
    for (int mt = 0; mt < 4; ++mt)
#pragma unroll
        for (int r = 0; r < 4; ++r) vmin[mt][r] = INFINITY;
    for (int t = 0; t < 9; ++t) {
        int i0 = (blockIdx.y * 9 + t) * 128;
        v4f acc[4][4];
#pragma unroll
        for (int mt = 0; mt < 4; ++mt)
#pragma unroll
            for (int nt = 0; nt < 4; ++nt)
#pragma unroll
                for (int r = 0; r < 4; ++r) acc[mt][nt][r] = 0.f;
        tile_mma(Ivb + (size_t)i0 * 512, Bsb, tid, fa, acc);  // acc = cos[j][i]
#pragma unroll
        for (int nt = 0; nt < 4; ++nt) {
            int i = i0 + wn * 64 + nt * 16 + l15;
            float mm = __uint_as_float(((unsigned*)(ws + OFF_MROW))[i]);
            float a = 2.0f / (mm + 1e-5f);
            float lw = __builtin_amdgcn_logf(ws[OFF_WROW + i]) * 0.6931471805599453f;
#pragma unroll
            for (int mt = 0; mt < 4; ++mt)
#pragma unroll
                for (int r = 0; r < 4; ++r) {
                    float d = fmaxf(0.5f - 0.5f * acc[mt][nt][r], 0.0f);
                    vmin[mt][r] = fminf(vmin[mt][r], a * d + lw);
                }
        }
    }
#pragma unroll
    for (int mt = 0; mt < 4; ++mt)
#pragma unroll
        for (int r = 0; r < 4; ++r) {
            float v = vmin[mt][r];
            for (int off = 1; off < 16; off <<= 1)
                v = fminf(v, __shfl_xor(v, off, 64));
            if (l15 == 0)
                atomicMin((unsigned*)(ws + OFF_VCOL) + j0 + wm * 64 + mt * 16 + quad * 4 + r,
                          __float_as_uint(v));
        }
}

// ---------------- final: loss = log(S) - log(sum_j exp(-vcol_j)) ----------
__global__ void k_final(const float* __restrict__ ws, float* __restrict__ out) {
    __shared__ float red[256];
    float s = 0.f;
    for (int j = threadIdx.x; j < Sn; j += 256)
        s += expf(-__uint_as_float(((const unsigned*)(ws + OFF_VCOL))[j]));
    red[threadIdx.x] = s;
    __syncthreads();
    for (int off = 128; off > 0; off >>= 1) {
        if (threadIdx.x < off) red[threadIdx.x] += red[threadIdx.x + off];
        __syncthreads();
    }
    if (threadIdx.x == 0) out[0] = logf((float)Sn) - logf(red[0]);
}

extern "C" void kernel_launch(void* const* d_in, const int* in_sizes, int n_in,
                              void* d_out, int out_size, void* d_ws, size_t ws_size,
                              hipStream_t stream) {
    const float* I = (const float*)d_in[0];
    const float* T = (const float*)d_in[1];
    float* ws = (float*)d_ws;
    float* out = (float*)d_out;

    k_init<<<36, 256, 0, stream>>>(ws);
    k_mean<<<Cn, 256, 0, stream>>>(T, ws);
    k_norm<<<Sn / 256, 256, 0, stream>>>(I, T, ws);
    k_rowmin<<<dim3(72, 8), 256, 0, stream>>>(ws);
    k_rowsum<<<dim3(72, 8), 256, 0, stream>>>(ws);
    k_colmin<<<dim3(72, 8), 256, 0, stream>>>(ws);
    k_final<<<1, 256, 0, stream>>>(ws, out);
}